// Round 9
// baseline (712.199 us; speedup 1.0000x reference)
//
#include <hip/hip_runtime.h>

#define NREL 3

// ===========================================================================
// Node-type tables for layer 0:
//   T[r][type][24]  = x0(type) @ W0_r          (873 KB, L2/L3-resident)
//   Troot[type][24] = x0(type) @ root0 + b0    (291 KB)
// ===========================================================================
__global__ void k_tables2(const float* __restrict__ size_emb,  // [ns,4]
                          const float* __restrict__ code_emb,  // [nc,32]
                          const float* __restrict__ w0,        // [3,36,24]
                          const float* __restrict__ root0,     // [36,24]
                          const float* __restrict__ b0,        // [24]
                          float* __restrict__ T, float* __restrict__ Troot,
                          int ns, int nc)
{
    int ntype = ns * nc;
    int tid = blockIdx.x * blockDim.x + threadIdx.x;
    int tot1 = NREL * ntype * 24;
    if (tid < tot1) {
        int d = tid % 24;
        int sc = (tid / 24) % ntype;
        int r = tid / (24 * ntype);
        int sz = sc / nc, cd = sc % nc;
        float a = 0.f;
        #pragma unroll
        for (int k = 0; k < 4; ++k)  a += size_emb[sz*4+k] * w0[(r*36+k)*24+d];
        for (int k = 0; k < 32; ++k) a += code_emb[cd*32+k] * w0[(r*36+4+k)*24+d];
        T[tid] = a;
    } else if (tid < tot1 + ntype * 24) {
        int t = tid - tot1;
        int d = t % 24;
        int sc = t / 24;
        int sz = sc / nc, cd = sc % nc;
        float a = b0[d];
        #pragma unroll
        for (int k = 0; k < 4; ++k)  a += size_emb[sz*4+k] * root0[k*24+d];
        for (int k = 0; k < 32; ++k) a += code_emb[cd*32+k] * root0[(4+k)*24+d];
        Troot[t] = a;
    }
}

// ===========================================================================
// Degree count (total per dst; per-rel counts are recomputed in pull loops)
// ===========================================================================
__global__ void k_count(const int* __restrict__ dst, int* __restrict__ cnt, int E)
{
    int e = blockIdx.x * blockDim.x + threadIdx.x;
    if (e < E) atomicAdd(&cnt[dst[e]], 1);
}

// ===========================================================================
// Degree-bucket histogram (ballot-based; no LDS atomics).
// bucket = min(deg, 31).
// ===========================================================================
__global__ void k_hist(const int* __restrict__ cnt, int* __restrict__ hist, int n)
{
    int i = blockIdx.x * 256 + threadIdx.x;
    int lane = threadIdx.x & 63, wid = threadIdx.x >> 6;
    int bucket = 32;                       // sentinel: out of range
    if (i < n) bucket = min(cnt[i], 31);
    __shared__ int wc[32 * 4];
    for (int b = 0; b < 32; ++b) {
        unsigned long long mk = __ballot(bucket == b);
        if (lane == 0) wc[b*4 + wid] = __popcll(mk);
    }
    __syncthreads();
    if (threadIdx.x < 32) {
        int b = threadIdx.x;
        int t = wc[b*4] + wc[b*4+1] + wc[b*4+2] + wc[b*4+3];
        if (t) atomicAdd(&hist[b], t);
    }
}

// exclusive scan of 32 bucket counts -> bucketFill bases (serial, trivial)
__global__ void k_base(const int* __restrict__ hist, int* __restrict__ bucketFill)
{
    if (threadIdx.x == 0 && blockIdx.x == 0) {
        int acc = 0;
        for (int b = 0; b < 32; ++b) { bucketFill[b] = acc; acc += hist[b]; }
    }
}

// ===========================================================================
// Ranked permutation: pos = bucketBase + blockOffset + waveOffset + laneRank.
// Writes perm, inv_perm, degP (permuted degrees), key2p (permuted node type).
// ===========================================================================
__global__ void __launch_bounds__(256) k_perm(
    const int* __restrict__ cnt,
    const int* __restrict__ x_size, const int* __restrict__ x_code,
    int* __restrict__ bucketFill,
    int* __restrict__ perm, int* __restrict__ inv_perm,
    int* __restrict__ degP, int* __restrict__ key2p, int n, int nc)
{
    int i = blockIdx.x * 256 + threadIdx.x;
    int lane = threadIdx.x & 63, wid = threadIdx.x >> 6;
    int deg = 0, bucket = 32;
    if (i < n) { deg = cnt[i]; bucket = min(deg, 31); }

    __shared__ int wc[32 * 4];   // per-bucket per-wave counts
    __shared__ int wb[32 * 4];   // per-bucket wave prefix
    __shared__ int bb[32];       // per-bucket block base (global)
    int rank = 0;
    for (int b = 0; b < 32; ++b) {
        unsigned long long mk = __ballot(bucket == b);
        if (lane == 0) wc[b*4 + wid] = __popcll(mk);
        if (b == bucket) rank = __popcll(mk & ((1ull << lane) - 1ull));
    }
    __syncthreads();
    if (threadIdx.x < 32) {
        int b = threadIdx.x;
        int c0 = wc[b*4], c1 = wc[b*4+1], c2 = wc[b*4+2], c3 = wc[b*4+3];
        int tot = c0 + c1 + c2 + c3;
        bb[b] = tot ? atomicAdd(&bucketFill[b], tot) : 0;
        wb[b*4+0] = 0; wb[b*4+1] = c0; wb[b*4+2] = c0+c1; wb[b*4+3] = c0+c1+c2;
    }
    __syncthreads();
    if (i < n) {
        int pos = bb[bucket] + wb[bucket*4 + wid] + rank;
        perm[pos] = i;
        inv_perm[i] = pos;
        degP[pos] = deg;
        key2p[pos] = x_size[i] * nc + x_code[i];
    }
}

// ===========================================================================
// Exclusive scan over permuted degrees -> rowptrP (+rowfillP copy)
// ===========================================================================
__global__ void kscan1(const int* __restrict__ degP, int* __restrict__ partials, int n)
{
    __shared__ int s[256];
    int t = threadIdx.x;
    int base = blockIdx.x * 1024 + t * 4;
    int sum = 0;
    #pragma unroll
    for (int j = 0; j < 4; ++j) {
        int node = base + j;
        if (node < n) sum += degP[node];
    }
    s[t] = sum; __syncthreads();
    for (int off = 128; off > 0; off >>= 1) {
        if (t < off) s[t] += s[t + off];
        __syncthreads();
    }
    if (t == 0) partials[blockIdx.x] = s[0];
}

__global__ void kscan2(int* partials, int np)
{
    __shared__ int s[1024];
    int t = threadIdx.x;
    int v = (t < np) ? partials[t] : 0;
    s[t] = v; __syncthreads();
    for (int off = 1; off < 1024; off <<= 1) {
        int a = (t >= off) ? s[t - off] : 0;
        __syncthreads();
        s[t] += a; __syncthreads();
    }
    if (t < np) partials[t] = s[t] - v;  // exclusive
}

__global__ void kscan3(const int* __restrict__ degP, const int* __restrict__ partials,
                       int* __restrict__ rowptr, int* __restrict__ rowfill, int n, int E)
{
    __shared__ int s[256];
    int t = threadIdx.x;
    int base = blockIdx.x * 1024 + t * 4;
    int d0 = 0, d1 = 0, d2 = 0, d3 = 0;
    if (base + 0 < n) d0 = degP[base+0];
    if (base + 1 < n) d1 = degP[base+1];
    if (base + 2 < n) d2 = degP[base+2];
    if (base + 3 < n) d3 = degP[base+3];
    int tsum = d0 + d1 + d2 + d3;
    s[t] = tsum; __syncthreads();
    for (int off = 1; off < 256; off <<= 1) {
        int a = (t >= off) ? s[t - off] : 0;
        __syncthreads();
        s[t] += a; __syncthreads();
    }
    int excl = s[t] - tsum + partials[blockIdx.x];
    if (base + 0 < n) { rowptr[base+0] = excl;            rowfill[base+0] = excl; }
    if (base + 1 < n) { rowptr[base+1] = excl+d0;         rowfill[base+1] = excl+d0; }
    if (base + 2 < n) { rowptr[base+2] = excl+d0+d1;      rowfill[base+2] = excl+d0+d1; }
    if (base + 3 < n) { rowptr[base+3] = excl+d0+d1+d2;   rowfill[base+3] = excl+d0+d1+d2; }
    if (blockIdx.x == 0 && t == 0) rowptr[n] = E;
}

// ===========================================================================
// CSR fill in PERMUTED space. slot = inv_perm[src] (20b) | et<<20 (2b), 4 B.
// No scale stored: per-rel counts recomputed in pull loops.
// ===========================================================================
__global__ void k_fill(const int* __restrict__ src, const int* __restrict__ dst,
                       const int* __restrict__ et, const int* __restrict__ inv_perm,
                       int* __restrict__ rowfill, unsigned* __restrict__ edges, int E)
{
    int e = blockIdx.x * blockDim.x + threadIdx.x;
    if (e >= E) return;
    int jd = inv_perm[dst[e]];
    int pos = atomicAdd(&rowfill[jd], 1);
    edges[pos] = (unsigned)inv_perm[src[e]] | ((unsigned)et[e] << 20);
}

// ===========================================================================
// Layer 0, pull, permuted space. Two passes over the row:
//   pass1 counts per-rel; pass2 single 24-reg accumulator, 24 FMA/edge,
//   scale selected per edge (T already folds W_r -> no per-rel accumulators).
// ===========================================================================
__global__ void __launch_bounds__(256) k_layer0_pull(
    const int* __restrict__ key2p,
    const int* __restrict__ rowptr, const unsigned* __restrict__ edges,
    const float* __restrict__ T,      // [3*ntype*24]
    const float* __restrict__ Troot,  // [ntype*24]
    float* __restrict__ xout, int n, int ntype)
{
    int j = blockIdx.x * blockDim.x + threadIdx.x;
    if (j >= n) return;

    int e0 = rowptr[j], e1 = rowptr[j+1];
    int c0 = 0, c1 = 0, c2 = 0;
    for (int e = e0; e < e1; ++e) {
        int r = edges[e] >> 20;
        c0 += (r == 0); c1 += (r == 1); c2 += (r == 2);
    }
    float inv0 = 1.f / fmaxf((float)c0, 1.f);
    float inv1 = 1.f / fmaxf((float)c1, 1.f);
    float inv2 = 1.f / fmaxf((float)c2, 1.f);

    float acc[24];
    {
        const float4* tr = (const float4*)(Troot + (size_t)key2p[j] * 24);
        #pragma unroll
        for (int q = 0; q < 6; ++q) {
            float4 v = tr[q];
            acc[q*4+0]=v.x; acc[q*4+1]=v.y; acc[q*4+2]=v.z; acc[q*4+3]=v.w;
        }
    }
    for (int e = e0; e < e1; ++e) {
        unsigned sl = edges[e];
        int s = sl & 0xFFFFF;
        int r = sl >> 20;
        float w = (r == 0) ? inv0 : ((r == 1) ? inv1 : inv2);
        const float4* trow = (const float4*)(T + ((size_t)r * ntype + key2p[s]) * 24);
        #pragma unroll
        for (int q = 0; q < 6; ++q) {
            float4 v = trow[q];
            acc[q*4+0] = fmaf(v.x, w, acc[q*4+0]);
            acc[q*4+1] = fmaf(v.y, w, acc[q*4+1]);
            acc[q*4+2] = fmaf(v.z, w, acc[q*4+2]);
            acc[q*4+3] = fmaf(v.w, w, acc[q*4+3]);
        }
    }
    float4* o = (float4*)(xout + (size_t)j * 24);
    #pragma unroll
    for (int q = 0; q < 6; ++q)
        o[q] = make_float4(fmaxf(acc[q*4+0], 0.f), fmaxf(acc[q*4+1], 0.f),
                           fmaxf(acc[q*4+2], 0.f), fmaxf(acc[q*4+3], 0.f));
}

// ===========================================================================
// Layers 1..3, pull, permuted space. Per-rel VGPR accumulators (unscaled),
// counts folded into the branch arms, division applied once per node.
// FINAL scatters through perm and fuses the 4->2 linear.
// ===========================================================================
template<int DIN, int DOUT, bool FINAL>
__global__ void __launch_bounds__(256) k_layer_pull(
    const float* __restrict__ xin,
    float* __restrict__ xout,
    const int* __restrict__ rowptr, const unsigned* __restrict__ edges,
    const float* __restrict__ W,     // [3,DIN,DOUT]
    const float* __restrict__ root,  // [DIN,DOUT]
    const float* __restrict__ bias,  // [DOUT]
    const float* __restrict__ linw,  // [4,2]
    const float* __restrict__ linb,  // [2]
    const int* __restrict__ perm,
    float* __restrict__ finout, int n)
{
    int j = blockIdx.x * blockDim.x + threadIdx.x;
    if (j >= n) return;

    float a0[DIN], a1[DIN], a2[DIN];
    #pragma unroll
    for (int k = 0; k < DIN; ++k) { a0[k] = 0.f; a1[k] = 0.f; a2[k] = 0.f; }
    int c0 = 0, c1 = 0, c2 = 0;

    int e0 = rowptr[j], e1 = rowptr[j+1];
    for (int e = e0; e < e1; ++e) {
        unsigned sl = edges[e];
        int s = sl & 0xFFFFF;
        int r = sl >> 20;
        const float4* p = (const float4*)(xin + (size_t)s * DIN);
        float xs[DIN];
        #pragma unroll
        for (int q = 0; q < DIN/4; ++q) {
            float4 v = p[q];
            xs[q*4+0]=v.x; xs[q*4+1]=v.y; xs[q*4+2]=v.z; xs[q*4+3]=v.w;
        }
        if (r == 0) {
            ++c0;
            #pragma unroll
            for (int k = 0; k < DIN; ++k) a0[k] += xs[k];
        } else if (r == 1) {
            ++c1;
            #pragma unroll
            for (int k = 0; k < DIN; ++k) a1[k] += xs[k];
        } else {
            ++c2;
            #pragma unroll
            for (int k = 0; k < DIN; ++k) a2[k] += xs[k];
        }
    }
    {
        float inv0 = 1.f / fmaxf((float)c0, 1.f);
        float inv1 = 1.f / fmaxf((float)c1, 1.f);
        float inv2 = 1.f / fmaxf((float)c2, 1.f);
        #pragma unroll
        for (int k = 0; k < DIN; ++k) { a0[k] *= inv0; a1[k] *= inv1; a2[k] *= inv2; }
    }

    float o[DOUT];
    #pragma unroll
    for (int d = 0; d < DOUT; ++d) o[d] = bias[d];

    {   // self/root term
        const float4* p = (const float4*)(xin + (size_t)j * DIN);
        #pragma unroll
        for (int q = 0; q < DIN/4; ++q) {
            float4 v = p[q];
            #pragma unroll
            for (int jj = 0; jj < 4; ++jj) {
                float xv = (&v.x)[jj];
                #pragma unroll
                for (int d = 0; d < DOUT; ++d)
                    o[d] = fmaf(xv, root[(q*4+jj)*DOUT + d], o[d]);
            }
        }
    }
    #pragma unroll
    for (int k = 0; k < DIN; ++k) {
        #pragma unroll
        for (int d = 0; d < DOUT; ++d)
            o[d] = fmaf(a0[k], W[(0*DIN + k)*DOUT + d], o[d]);
    }
    #pragma unroll
    for (int k = 0; k < DIN; ++k) {
        #pragma unroll
        for (int d = 0; d < DOUT; ++d)
            o[d] = fmaf(a1[k], W[(1*DIN + k)*DOUT + d], o[d]);
    }
    #pragma unroll
    for (int k = 0; k < DIN; ++k) {
        #pragma unroll
        for (int d = 0; d < DOUT; ++d)
            o[d] = fmaf(a2[k], W[(2*DIN + k)*DOUT + d], o[d]);
    }
    #pragma unroll
    for (int d = 0; d < DOUT; ++d) o[d] = fmaxf(o[d], 0.f);

    if (FINAL) {                               // DOUT == 4; scatter via perm
        float o0 = linb[0], o1 = linb[1];
        #pragma unroll
        for (int k = 0; k < 4; ++k) {
            o0 = fmaf(o[k], linw[k*2+0], o0);
            o1 = fmaf(o[k], linw[k*2+1], o1);
        }
        int orig = perm[j];
        *(float2*)(finout + (size_t)orig * 2) = make_float2(o0, o1);
    } else {
        float* op = xout + (size_t)j * DOUT;
        #pragma unroll
        for (int q = 0; q < DOUT/4; ++q)
            ((float4*)op)[q] = make_float4(o[q*4+0], o[q*4+1], o[q*4+2], o[q*4+3]);
    }
}

// ===========================================================================
extern "C" void kernel_launch(void* const* d_in, const int* in_sizes, int n_in,
                              void* d_out, int out_size, void* d_ws, size_t ws_size,
                              hipStream_t stream)
{
    const int*   x_code    = (const int*)d_in[0];
    const int*   x_size    = (const int*)d_in[1];
    const int*   edge_index= (const int*)d_in[2];
    const int*   edge_type = (const int*)d_in[3];
    const float* size_emb  = (const float*)d_in[4];
    const float* code_emb  = (const float*)d_in[5];
    const float* w0 = (const float*)d_in[6];  const float* root0 = (const float*)d_in[7];  const float* b0 = (const float*)d_in[8];
    const float* w1 = (const float*)d_in[9];  const float* root1 = (const float*)d_in[10]; const float* b1 = (const float*)d_in[11];
    const float* w2 = (const float*)d_in[12]; const float* root2 = (const float*)d_in[13]; const float* b2 = (const float*)d_in[14];
    const float* w3 = (const float*)d_in[15]; const float* root3 = (const float*)d_in[16]; const float* b3 = (const float*)d_in[17];
    const float* lin_w = (const float*)d_in[18];
    const float* lin_b = (const float*)d_in[19];

    int n  = in_sizes[0];
    int E  = in_sizes[3];
    int ns = in_sizes[4] / 4;    // 15
    int nc = in_sizes[5] / 32;   // 202
    int ntype = ns * nc;         // 3030
    const int* esrc = edge_index;
    const int* edst = edge_index + E;

    // workspace carve-up (~190 MB)
    char* ws = (char*)d_ws;
    size_t off = 0;
    auto alloc = [&](size_t bytes) -> void* {
        void* p = ws + off;
        off = (off + bytes + 255) & ~(size_t)255;
        return p;
    };
    float*    bufA     = (float*)   alloc((size_t)n * 24 * 4);   // x1p, later x3p
    float*    bufB     = (float*)   alloc((size_t)n * 16 * 4);   // x2p
    int*      rowptrP  = (int*)     alloc(((size_t)n + 1) * 4);
    int*      rowfillP = (int*)     alloc((size_t)n * 4);
    unsigned* edges    = (unsigned*)alloc((size_t)E * 4);        // 4B slots
    int*      cnt      = (int*)     alloc((size_t)n * 4);
    int*      perm     = (int*)     alloc((size_t)n * 4);
    int*      inv_perm = (int*)     alloc((size_t)n * 4);
    int*      degP     = (int*)     alloc((size_t)n * 4);
    int*      key2p    = (int*)     alloc((size_t)n * 4);
    int*      partials = (int*)     alloc(4096 * 4);
    int*      hist     = (int*)     alloc(32 * 4);
    int*      bucketFill=(int*)     alloc(32 * 4);
    float*    T        = (float*)   alloc((size_t)NREL * ntype * 24 * 4);
    float*    Troot    = (float*)   alloc((size_t)ntype * 24 * 4);

    hipMemsetAsync(cnt, 0, (size_t)n * 4, stream);
    hipMemsetAsync(hist, 0, 32 * 4, stream);

    const int tb = 256;
    int tableThreads = NREL*ntype*24 + ntype*24;
    k_tables2<<<(tableThreads + tb - 1)/tb, tb, 0, stream>>>(
        size_emb, code_emb, w0, root0, b0, T, Troot, ns, nc);

    k_count<<<(E + tb - 1)/tb, tb, 0, stream>>>(edst, cnt, E);

    int g256 = (n + 255) / 256;
    k_hist<<<g256, tb, 0, stream>>>(cnt, hist, n);
    k_base<<<1, 64, 0, stream>>>(hist, bucketFill);
    k_perm<<<g256, tb, 0, stream>>>(cnt, x_size, x_code, bucketFill,
                                    perm, inv_perm, degP, key2p, n, nc);

    int nblk = (n + 1023) / 1024;   // 977 for n=1e6 (<=1024)
    kscan1<<<nblk, 256, 0, stream>>>(degP, partials, n);
    kscan2<<<1, 1024, 0, stream>>>(partials, nblk);
    kscan3<<<nblk, 256, 0, stream>>>(degP, partials, rowptrP, rowfillP, n, E);

    k_fill<<<(E + tb - 1)/tb, tb, 0, stream>>>(esrc, edst, edge_type, inv_perm,
                                               rowfillP, edges, E);

    k_layer0_pull<<<g256, tb, 0, stream>>>(key2p, rowptrP, edges, T, Troot, bufA, n, ntype);
    k_layer_pull<24,16,false><<<g256, tb, 0, stream>>>(bufA, bufB, rowptrP, edges,
                                                 w1, root1, b1, nullptr, nullptr, nullptr, nullptr, n);
    k_layer_pull<16, 8,false><<<g256, tb, 0, stream>>>(bufB, bufA, rowptrP, edges,
                                                 w2, root2, b2, nullptr, nullptr, nullptr, nullptr, n);
    k_layer_pull< 8, 4,true ><<<g256, tb, 0, stream>>>(bufA, nullptr, rowptrP, edges,
                                                 w3, root3, b3, lin_w, lin_b, perm, (float*)d_out, n);
}

// Round 11
// 587.043 us; speedup vs baseline: 1.2132x; 1.2132x over previous
//
#include <hip/hip_runtime.h>
#include <hip/hip_fp16.h>

#define NREL 3

// ---------------------------------------------------------------------------
// fp16 pack/unpack helpers (storage fp16, math fp32)
// ---------------------------------------------------------------------------
__device__ __forceinline__ void unpack8(uint4 v, float* o) {
    *(float2*)(o+0) = __half22float2(*(__half2*)&v.x);
    *(float2*)(o+2) = __half22float2(*(__half2*)&v.y);
    *(float2*)(o+4) = __half22float2(*(__half2*)&v.z);
    *(float2*)(o+6) = __half22float2(*(__half2*)&v.w);
}
__device__ __forceinline__ unsigned pack2(float a, float b) {
    __half2 h = __floats2half2_rn(a, b);
    return *(unsigned*)&h;
}

// ===========================================================================
// Node-type tables for layer 0 (fp32; L2-resident):
//   T[r][type][24]  = x0(type) @ W0_r
//   Troot[type][24] = x0(type) @ root0 + b0
// ===========================================================================
__global__ void k_tables2(const float* __restrict__ size_emb,  // [ns,4]
                          const float* __restrict__ code_emb,  // [nc,32]
                          const float* __restrict__ w0,        // [3,36,24]
                          const float* __restrict__ root0,     // [36,24]
                          const float* __restrict__ b0,        // [24]
                          float* __restrict__ T, float* __restrict__ Troot,
                          int ns, int nc)
{
    int ntype = ns * nc;
    int tid = blockIdx.x * blockDim.x + threadIdx.x;
    int tot1 = NREL * ntype * 24;
    if (tid < tot1) {
        int d = tid % 24;
        int sc = (tid / 24) % ntype;
        int r = tid / (24 * ntype);
        int sz = sc / nc, cd = sc % nc;
        float a = 0.f;
        #pragma unroll
        for (int k = 0; k < 4; ++k)  a += size_emb[sz*4+k] * w0[(r*36+k)*24+d];
        for (int k = 0; k < 32; ++k) a += code_emb[cd*32+k] * w0[(r*36+4+k)*24+d];
        T[tid] = a;
    } else if (tid < tot1 + ntype * 24) {
        int t = tid - tot1;
        int d = t % 24;
        int sc = t / 24;
        int sz = sc / nc, cd = sc % nc;
        float a = b0[d];
        #pragma unroll
        for (int k = 0; k < 4; ++k)  a += size_emb[sz*4+k] * root0[k*24+d];
        for (int k = 0; k < 32; ++k) a += code_emb[cd*32+k] * root0[(4+k)*24+d];
        Troot[t] = a;
    }
}

__global__ void k_key(const int* __restrict__ x_size, const int* __restrict__ x_code,
                      int* __restrict__ key2, int n, int nc)
{
    int i = blockIdx.x * blockDim.x + threadIdx.x;
    if (i < n) key2[i] = x_size[i] * nc + x_code[i];
}

// ===========================================================================
// CSR build (original node space, 4B slots, no stored scale)
// ===========================================================================
__global__ void k_count(const int* __restrict__ dst, int* __restrict__ cnt, int E)
{
    int e = blockIdx.x * blockDim.x + threadIdx.x;
    if (e < E) atomicAdd(&cnt[dst[e]], 1);
}

__global__ void kscan1(const int* __restrict__ cnt, int* __restrict__ partials, int n)
{
    __shared__ int s[256];
    int t = threadIdx.x;
    int base = blockIdx.x * 1024 + t * 4;
    int sum = 0;
    #pragma unroll
    for (int j = 0; j < 4; ++j) {
        int node = base + j;
        if (node < n) sum += cnt[node];
    }
    s[t] = sum; __syncthreads();
    for (int off = 128; off > 0; off >>= 1) {
        if (t < off) s[t] += s[t + off];
        __syncthreads();
    }
    if (t == 0) partials[blockIdx.x] = s[0];
}

__global__ void kscan2(int* partials, int np)
{
    __shared__ int s[1024];
    int t = threadIdx.x;
    int v = (t < np) ? partials[t] : 0;
    s[t] = v; __syncthreads();
    for (int off = 1; off < 1024; off <<= 1) {
        int a = (t >= off) ? s[t - off] : 0;
        __syncthreads();
        s[t] += a; __syncthreads();
    }
    if (t < np) partials[t] = s[t] - v;  // exclusive
}

__global__ void kscan3(const int* __restrict__ cnt, const int* __restrict__ partials,
                       int* __restrict__ rowptr, int* __restrict__ rowfill, int n, int E)
{
    __shared__ int s[256];
    int t = threadIdx.x;
    int base = blockIdx.x * 1024 + t * 4;
    int d0 = 0, d1 = 0, d2 = 0, d3 = 0;
    if (base + 0 < n) d0 = cnt[base+0];
    if (base + 1 < n) d1 = cnt[base+1];
    if (base + 2 < n) d2 = cnt[base+2];
    if (base + 3 < n) d3 = cnt[base+3];
    int tsum = d0 + d1 + d2 + d3;
    s[t] = tsum; __syncthreads();
    for (int off = 1; off < 256; off <<= 1) {
        int a = (t >= off) ? s[t - off] : 0;
        __syncthreads();
        s[t] += a; __syncthreads();
    }
    int excl = s[t] - tsum + partials[blockIdx.x];
    if (base + 0 < n) { rowptr[base+0] = excl;            rowfill[base+0] = excl; }
    if (base + 1 < n) { rowptr[base+1] = excl+d0;         rowfill[base+1] = excl+d0; }
    if (base + 2 < n) { rowptr[base+2] = excl+d0+d1;      rowfill[base+2] = excl+d0+d1; }
    if (base + 3 < n) { rowptr[base+3] = excl+d0+d1+d2;   rowfill[base+3] = excl+d0+d1+d2; }
    if (blockIdx.x == 0 && t == 0) rowptr[n] = E;
}

__global__ void k_fill(const int* __restrict__ src, const int* __restrict__ dst,
                       const int* __restrict__ et,
                       int* __restrict__ rowfill, unsigned* __restrict__ edges, int E)
{
    int e = blockIdx.x * blockDim.x + threadIdx.x;
    if (e >= E) return;
    int pos = atomicAdd(&rowfill[dst[e]], 1);
    edges[pos] = (unsigned)src[e] | ((unsigned)et[e] << 20);
}

// ===========================================================================
// Layer 0, pull: two passes over the row (count rels, then accumulate).
// T folds W_r -> single 24-reg accumulator.  Output fp16.
// ===========================================================================
__global__ void __launch_bounds__(256) k_layer0_pull(
    const int* __restrict__ key2,
    const int* __restrict__ rowptr, const unsigned* __restrict__ edges,
    const float* __restrict__ T,      // [3*ntype*24]
    const float* __restrict__ Troot,  // [ntype*24]
    __half* __restrict__ xout, int n, int ntype)
{
    int i = blockIdx.x * blockDim.x + threadIdx.x;
    if (i >= n) return;

    int e0 = rowptr[i], e1 = rowptr[i+1];
    int c0 = 0, c1 = 0, c2 = 0;
    for (int e = e0; e < e1; ++e) {
        int r = edges[e] >> 20;
        c0 += (r == 0); c1 += (r == 1); c2 += (r == 2);
    }
    float inv0 = 1.f / fmaxf((float)c0, 1.f);
    float inv1 = 1.f / fmaxf((float)c1, 1.f);
    float inv2 = 1.f / fmaxf((float)c2, 1.f);

    float acc[24];
    {
        const float4* tr = (const float4*)(Troot + (size_t)key2[i] * 24);
        #pragma unroll
        for (int q = 0; q < 6; ++q) {
            float4 v = tr[q];
            acc[q*4+0]=v.x; acc[q*4+1]=v.y; acc[q*4+2]=v.z; acc[q*4+3]=v.w;
        }
    }
    for (int e = e0; e < e1; ++e) {
        unsigned sl = edges[e];
        int s = sl & 0xFFFFF;
        int r = sl >> 20;
        float w = (r == 0) ? inv0 : ((r == 1) ? inv1 : inv2);
        const float4* trow = (const float4*)(T + ((size_t)r * ntype + key2[s]) * 24);
        #pragma unroll
        for (int q = 0; q < 6; ++q) {
            float4 v = trow[q];
            acc[q*4+0] = fmaf(v.x, w, acc[q*4+0]);
            acc[q*4+1] = fmaf(v.y, w, acc[q*4+1]);
            acc[q*4+2] = fmaf(v.z, w, acc[q*4+2]);
            acc[q*4+3] = fmaf(v.w, w, acc[q*4+3]);
        }
    }
    unsigned ow[12];
    #pragma unroll
    for (int q = 0; q < 12; ++q)
        ow[q] = pack2(fmaxf(acc[2*q], 0.f), fmaxf(acc[2*q+1], 0.f));
    uint4* op = (uint4*)(xout + (size_t)i * 24);
    #pragma unroll
    for (int q = 0; q < 3; ++q) op[q] = ((uint4*)ow)[q];
}

// ===========================================================================
// Layers 1..3, pull: fp16 feature gathers, fp32 accumulate; per-rel VGPR
// accumulators (3-way branch); counts folded in, divide once per node.
// Weights fp32 with uniform indices -> scalar-pipe s_load.
// ===========================================================================
template<int DIN, int DOUT, bool FINAL>
__global__ void __launch_bounds__(256) k_layer_pull(
    const __half* __restrict__ xin,
    __half* __restrict__ xout,
    const int* __restrict__ rowptr, const unsigned* __restrict__ edges,
    const float* __restrict__ W,     // [3,DIN,DOUT]
    const float* __restrict__ root,  // [DIN,DOUT]
    const float* __restrict__ bias,  // [DOUT]
    const float* __restrict__ linw,  // [4,2]
    const float* __restrict__ linb,  // [2]
    float* __restrict__ finout, int n)
{
    int j = blockIdx.x * blockDim.x + threadIdx.x;
    if (j >= n) return;

    float a0[DIN], a1[DIN], a2[DIN];
    #pragma unroll
    for (int k = 0; k < DIN; ++k) { a0[k] = 0.f; a1[k] = 0.f; a2[k] = 0.f; }
    int c0 = 0, c1 = 0, c2 = 0;

    int e0 = rowptr[j], e1 = rowptr[j+1];
    for (int e = e0; e < e1; ++e) {
        unsigned sl = edges[e];
        int s = sl & 0xFFFFF;
        int r = sl >> 20;
        const uint4* p = (const uint4*)(xin + (size_t)s * DIN);
        float xs[DIN];
        #pragma unroll
        for (int q = 0; q < DIN/8; ++q) unpack8(p[q], xs + q*8);
        if (r == 0) {
            ++c0;
            #pragma unroll
            for (int k = 0; k < DIN; ++k) a0[k] += xs[k];
        } else if (r == 1) {
            ++c1;
            #pragma unroll
            for (int k = 0; k < DIN; ++k) a1[k] += xs[k];
        } else {
            ++c2;
            #pragma unroll
            for (int k = 0; k < DIN; ++k) a2[k] += xs[k];
        }
    }
    {
        float inv0 = 1.f / fmaxf((float)c0, 1.f);
        float inv1 = 1.f / fmaxf((float)c1, 1.f);
        float inv2 = 1.f / fmaxf((float)c2, 1.f);
        #pragma unroll
        for (int k = 0; k < DIN; ++k) { a0[k] *= inv0; a1[k] *= inv1; a2[k] *= inv2; }
    }

    float o[DOUT];
    #pragma unroll
    for (int d = 0; d < DOUT; ++d) o[d] = bias[d];

    {   // self/root term
        const uint4* p = (const uint4*)(xin + (size_t)j * DIN);
        float xi[DIN];
        #pragma unroll
        for (int q = 0; q < DIN/8; ++q) unpack8(p[q], xi + q*8);
        #pragma unroll
        for (int k = 0; k < DIN; ++k) {
            #pragma unroll
            for (int d = 0; d < DOUT; ++d)
                o[d] = fmaf(xi[k], root[k*DOUT + d], o[d]);
        }
    }
    #pragma unroll
    for (int k = 0; k < DIN; ++k) {
        #pragma unroll
        for (int d = 0; d < DOUT; ++d)
            o[d] = fmaf(a0[k], W[(0*DIN + k)*DOUT + d], o[d]);
    }
    #pragma unroll
    for (int k = 0; k < DIN; ++k) {
        #pragma unroll
        for (int d = 0; d < DOUT; ++d)
            o[d] = fmaf(a1[k], W[(1*DIN + k)*DOUT + d], o[d]);
    }
    #pragma unroll
    for (int k = 0; k < DIN; ++k) {
        #pragma unroll
        for (int d = 0; d < DOUT; ++d)
            o[d] = fmaf(a2[k], W[(2*DIN + k)*DOUT + d], o[d]);
    }
    #pragma unroll
    for (int d = 0; d < DOUT; ++d) o[d] = fmaxf(o[d], 0.f);

    if (FINAL) {                               // DOUT == 4; fp32 output
        float o0 = linb[0], o1 = linb[1];
        #pragma unroll
        for (int k = 0; k < 4; ++k) {
            o0 = fmaf(o[k], linw[k*2+0], o0);
            o1 = fmaf(o[k], linw[k*2+1], o1);
        }
        *(float2*)(finout + (size_t)j * 2) = make_float2(o0, o1);
    } else {
        unsigned ow[DOUT/2];
        #pragma unroll
        for (int q = 0; q < DOUT/2; ++q) ow[q] = pack2(o[2*q], o[2*q+1]);
        uint4* op = (uint4*)(xout + (size_t)j * DOUT);
        #pragma unroll
        for (int q = 0; q < DOUT/8; ++q) op[q] = ((uint4*)ow)[q];
    }
}

// ===========================================================================
extern "C" void kernel_launch(void* const* d_in, const int* in_sizes, int n_in,
                              void* d_out, int out_size, void* d_ws, size_t ws_size,
                              hipStream_t stream)
{
    const int*   x_code    = (const int*)d_in[0];
    const int*   x_size    = (const int*)d_in[1];
    const int*   edge_index= (const int*)d_in[2];
    const int*   edge_type = (const int*)d_in[3];
    const float* size_emb  = (const float*)d_in[4];
    const float* code_emb  = (const float*)d_in[5];
    const float* w0 = (const float*)d_in[6];  const float* root0 = (const float*)d_in[7];  const float* b0 = (const float*)d_in[8];
    const float* w1 = (const float*)d_in[9];  const float* root1 = (const float*)d_in[10]; const float* b1 = (const float*)d_in[11];
    const float* w2 = (const float*)d_in[12]; const float* root2 = (const float*)d_in[13]; const float* b2 = (const float*)d_in[14];
    const float* w3 = (const float*)d_in[15]; const float* root3 = (const float*)d_in[16]; const float* b3 = (const float*)d_in[17];
    const float* lin_w = (const float*)d_in[18];
    const float* lin_b = (const float*)d_in[19];

    int n  = in_sizes[0];
    int E  = in_sizes[3];
    int ns = in_sizes[4] / 4;    // 15
    int nc = in_sizes[5] / 32;   // 202
    int ntype = ns * nc;         // 3030
    const int* esrc = edge_index;
    const int* edst = edge_index + E;

    // workspace carve-up (~110 MB)
    char* ws = (char*)d_ws;
    size_t off = 0;
    auto alloc = [&](size_t bytes) -> void* {
        void* p = ws + off;
        off = (off + bytes + 255) & ~(size_t)255;
        return p;
    };
    __half*   bufA     = (__half*)  alloc((size_t)n * 24 * 2);   // x1, later x3
    __half*   bufB     = (__half*)  alloc((size_t)n * 16 * 2);   // x2
    int*      rowptr   = (int*)     alloc(((size_t)n + 1) * 4);
    int*      rowfill  = (int*)     alloc((size_t)n * 4);
    unsigned* edges    = (unsigned*)alloc((size_t)E * 4);        // 4B slots
    int*      cnt      = (int*)     alloc((size_t)n * 4);
    int*      key2     = (int*)     alloc((size_t)n * 4);
    int*      partials = (int*)     alloc(4096 * 4);
    float*    T        = (float*)   alloc((size_t)NREL * ntype * 24 * 4);
    float*    Troot    = (float*)   alloc((size_t)ntype * 24 * 4);

    hipMemsetAsync(cnt, 0, (size_t)n * 4, stream);

    const int tb = 256;
    int tableThreads = NREL*ntype*24 + ntype*24;
    k_tables2<<<(tableThreads + tb - 1)/tb, tb, 0, stream>>>(
        size_emb, code_emb, w0, root0, b0, T, Troot, ns, nc);
    k_key<<<(n + tb - 1)/tb, tb, 0, stream>>>(x_size, x_code, key2, n, nc);

    k_count<<<(E + tb - 1)/tb, tb, 0, stream>>>(edst, cnt, E);

    int nblk = (n + 1023) / 1024;   // 977 for n=1e6 (<=1024)
    kscan1<<<nblk, 256, 0, stream>>>(cnt, partials, n);
    kscan2<<<1, 1024, 0, stream>>>(partials, nblk);
    kscan3<<<nblk, 256, 0, stream>>>(cnt, partials, rowptr, rowfill, n, E);

    k_fill<<<(E + tb - 1)/tb, tb, 0, stream>>>(esrc, edst, edge_type,
                                               rowfill, edges, E);

    int g256 = (n + 255) / 256;
    k_layer0_pull<<<g256, tb, 0, stream>>>(key2, rowptr, edges, T, Troot, bufA, n, ntype);
    k_layer_pull<24,16,false><<<g256, tb, 0, stream>>>(bufA, bufB, rowptr, edges,
                                                 w1, root1, b1, nullptr, nullptr, nullptr, n);
    k_layer_pull<16, 8,false><<<g256, tb, 0, stream>>>(bufB, bufA, rowptr, edges,
                                                 w2, root2, b2, nullptr, nullptr, nullptr, n);
    k_layer_pull< 8, 4,true ><<<g256, tb, 0, stream>>>(bufA, nullptr, rowptr, edges,
                                                 w3, root3, b3, lin_w, lin_b, (float*)d_out, n);
}

// Round 12
// 432.557 us; speedup vs baseline: 1.6465x; 1.3571x over previous
//
#include <hip/hip_runtime.h>
#include <hip/hip_fp16.h>

#define NREL 3
#define EPB 2048                    // edges per partition block
#define BKT_SHIFT 10                // 1024 nodes per bucket
#define BKT_MASK ((1 << BKT_SHIFT) - 1)

// ---------------------------------------------------------------------------
// fp16 pack/unpack helpers (storage fp16, math fp32)
// ---------------------------------------------------------------------------
__device__ __forceinline__ void unpack8(uint4 v, float* o) {
    *(float2*)(o+0) = __half22float2(*(__half2*)&v.x);
    *(float2*)(o+2) = __half22float2(*(__half2*)&v.y);
    *(float2*)(o+4) = __half22float2(*(__half2*)&v.z);
    *(float2*)(o+6) = __half22float2(*(__half2*)&v.w);
}
__device__ __forceinline__ unsigned pack2(float a, float b) {
    __half2 h = __floats2half2_rn(a, b);
    return *(unsigned*)&h;
}

// ===========================================================================
// Node-type tables for layer 0 (fp32; L2-resident)
// ===========================================================================
__global__ void k_tables2(const float* __restrict__ size_emb,  // [ns,4]
                          const float* __restrict__ code_emb,  // [nc,32]
                          const float* __restrict__ w0,        // [3,36,24]
                          const float* __restrict__ root0,     // [36,24]
                          const float* __restrict__ b0,        // [24]
                          float* __restrict__ T, float* __restrict__ Troot,
                          int ns, int nc)
{
    int ntype = ns * nc;
    int tid = blockIdx.x * blockDim.x + threadIdx.x;
    int tot1 = NREL * ntype * 24;
    if (tid < tot1) {
        int d = tid % 24;
        int sc = (tid / 24) % ntype;
        int r = tid / (24 * ntype);
        int sz = sc / nc, cd = sc % nc;
        float a = 0.f;
        #pragma unroll
        for (int k = 0; k < 4; ++k)  a += size_emb[sz*4+k] * w0[(r*36+k)*24+d];
        for (int k = 0; k < 32; ++k) a += code_emb[cd*32+k] * w0[(r*36+4+k)*24+d];
        T[tid] = a;
    } else if (tid < tot1 + ntype * 24) {
        int t = tid - tot1;
        int d = t % 24;
        int sc = t / 24;
        int sz = sc / nc, cd = sc % nc;
        float a = b0[d];
        #pragma unroll
        for (int k = 0; k < 4; ++k)  a += size_emb[sz*4+k] * root0[k*24+d];
        for (int k = 0; k < 32; ++k) a += code_emb[cd*32+k] * root0[(4+k)*24+d];
        Troot[t] = a;
    }
}

__global__ void k_key(const int* __restrict__ x_size, const int* __restrict__ x_code,
                      int* __restrict__ key2, int n, int nc)
{
    int i = blockIdx.x * blockDim.x + threadIdx.x;
    if (i < n) key2[i] = x_size[i] * nc + x_code[i];
}

// ===========================================================================
// CSR build, atomic-free (no device atomics anywhere):
//  k_hist    : per-block bucket histogram (LDS)  -> histT[bucket][block]
//  kscan1/2/3: in-place exclusive scan of histT  -> exact (block,bucket) offsets
//  k_scatter : LDS-ranked scatter into bucket-partitioned tmp
//  k_csr     : per-bucket LDS count+scan -> rowptr slice + final placement
// ===========================================================================
__global__ void __launch_bounds__(256) k_hist(
    const int* __restrict__ dst, int* __restrict__ histT, int E, int NB, int NBK)
{
    __shared__ int h[1 << BKT_SHIFT];
    int bl = blockIdx.x;
    for (int t = threadIdx.x; t < (1 << BKT_SHIFT); t += 256) h[t] = 0;
    __syncthreads();
    int base = bl * EPB;
    #pragma unroll
    for (int it = 0; it < EPB / 256; ++it) {
        int e = base + it * 256 + (int)threadIdx.x;
        if (e < E) atomicAdd(&h[dst[e] >> BKT_SHIFT], 1);
    }
    __syncthreads();
    for (int b = threadIdx.x; b < NB; b += 256)
        histT[b * NBK + bl] = h[b];
}

__global__ void kscan1(const int* __restrict__ arr, int* __restrict__ partials, int m)
{
    __shared__ int s[256];
    int t = threadIdx.x;
    int base = blockIdx.x * 1024 + t * 4;
    int sum = 0;
    #pragma unroll
    for (int j = 0; j < 4; ++j) {
        int i = base + j;
        if (i < m) sum += arr[i];
    }
    s[t] = sum; __syncthreads();
    for (int off = 128; off > 0; off >>= 1) {
        if (t < off) s[t] += s[t + off];
        __syncthreads();
    }
    if (t == 0) partials[blockIdx.x] = s[0];
}

__global__ void kscan2(int* partials, int np)
{
    __shared__ int s[1024];
    int t = threadIdx.x;
    int v = (t < np) ? partials[t] : 0;
    s[t] = v; __syncthreads();
    for (int off = 1; off < 1024; off <<= 1) {
        int a = (t >= off) ? s[t - off] : 0;
        __syncthreads();
        s[t] += a; __syncthreads();
    }
    if (t < np) partials[t] = s[t] - v;  // exclusive
}

__global__ void kscan3(int* __restrict__ arr, const int* __restrict__ partials, int m)
{
    __shared__ int s[256];
    int t = threadIdx.x;
    int base = blockIdx.x * 1024 + t * 4;
    int d0 = 0, d1 = 0, d2 = 0, d3 = 0;
    if (base + 0 < m) d0 = arr[base+0];
    if (base + 1 < m) d1 = arr[base+1];
    if (base + 2 < m) d2 = arr[base+2];
    if (base + 3 < m) d3 = arr[base+3];
    int tsum = d0 + d1 + d2 + d3;
    s[t] = tsum; __syncthreads();
    for (int off = 1; off < 256; off <<= 1) {
        int a = (t >= off) ? s[t - off] : 0;
        __syncthreads();
        s[t] += a; __syncthreads();
    }
    int excl = s[t] - tsum + partials[blockIdx.x];
    if (base + 0 < m) arr[base+0] = excl;
    if (base + 1 < m) arr[base+1] = excl + d0;
    if (base + 2 < m) arr[base+2] = excl + d0 + d1;
    if (base + 3 < m) arr[base+3] = excl + d0 + d1 + d2;
}

// tmp word: src(20) | rel(2)<<20 | dstlocal(10)<<22
__global__ void __launch_bounds__(256) k_scatter(
    const int* __restrict__ src, const int* __restrict__ dst,
    const int* __restrict__ et, const int* __restrict__ offT,
    unsigned* __restrict__ tmp, int E, int NB, int NBK)
{
    __shared__ int h[1 << BKT_SHIFT];
    int bl = blockIdx.x;
    for (int t = threadIdx.x; t < (1 << BKT_SHIFT); t += 256) h[t] = 0;
    __syncthreads();
    int base = bl * EPB;
    #pragma unroll
    for (int it = 0; it < EPB / 256; ++it) {
        int e = base + it * 256 + (int)threadIdx.x;
        if (e < E) {
            int d = dst[e];
            int b = d >> BKT_SHIFT;
            int rank = atomicAdd(&h[b], 1);              // LDS rank (cumulative)
            int pos = offT[b * NBK + bl] + rank;
            tmp[pos] = (unsigned)src[e] | ((unsigned)et[e] << 20)
                     | ((unsigned)(d & BKT_MASK) << 22);
        }
    }
}

__global__ void __launch_bounds__(256) k_csr(
    const unsigned* __restrict__ tmp, const int* __restrict__ offT,
    int* __restrict__ rowptr, unsigned* __restrict__ edges,
    int n, int E, int NB, int NBK)
{
    __shared__ int cnt[1 << BKT_SHIFT];
    __shared__ int fil[1 << BKT_SHIFT];
    __shared__ int ws[256];
    int b = blockIdx.x;
    int eb = offT[b * NBK];
    int ee = (b + 1 < NB) ? offT[(b + 1) * NBK] : E;
    int node0 = b << BKT_SHIFT;

    for (int t = threadIdx.x; t < (1 << BKT_SHIFT); t += 256) cnt[t] = 0;
    __syncthreads();
    for (int e = eb + (int)threadIdx.x; e < ee; e += 256)
        atomicAdd(&cnt[tmp[e] >> 22], 1);
    __syncthreads();

    // block-exclusive scan of cnt[1024] with 256 threads (4 each)
    int t = threadIdx.x;
    int c0 = cnt[4*t+0], c1 = cnt[4*t+1], c2 = cnt[4*t+2], c3 = cnt[4*t+3];
    int tsum = c0 + c1 + c2 + c3;
    ws[t] = tsum; __syncthreads();
    for (int off = 1; off < 256; off <<= 1) {
        int a = (t >= off) ? ws[t - off] : 0;
        __syncthreads();
        ws[t] += a; __syncthreads();
    }
    int excl = ws[t] - tsum;
    fil[4*t+0] = excl;
    fil[4*t+1] = excl + c0;
    fil[4*t+2] = excl + c0 + c1;
    fil[4*t+3] = excl + c0 + c1 + c2;
    __syncthreads();

    // rowptr slice (coalesced); must complete before fil is mutated below
    for (int l = threadIdx.x; l < (1 << BKT_SHIFT); l += 256) {
        int node = node0 + l;
        if (node < n) rowptr[node] = eb + fil[l];
    }
    if (b == NB - 1 && threadIdx.x == 0) rowptr[n] = E;
    __syncthreads();

    // final placement into 8KB L2/L1-hot window
    for (int e = eb + (int)threadIdx.x; e < ee; e += 256) {
        unsigned w = tmp[e];
        int l = w >> 22;
        int pos = eb + atomicAdd(&fil[l], 1);
        edges[pos] = w & 0x3FFFFF;                      // src | rel<<20
    }
}

// ===========================================================================
// Layer 0, pull: two passes over the row (count rels, then accumulate).
// T folds W_r -> single 24-reg accumulator.  Output fp16.
// ===========================================================================
__global__ void __launch_bounds__(256) k_layer0_pull(
    const int* __restrict__ key2,
    const int* __restrict__ rowptr, const unsigned* __restrict__ edges,
    const float* __restrict__ T,      // [3*ntype*24]
    const float* __restrict__ Troot,  // [ntype*24]
    __half* __restrict__ xout, int n, int ntype)
{
    int i = blockIdx.x * blockDim.x + threadIdx.x;
    if (i >= n) return;

    int e0 = rowptr[i], e1 = rowptr[i+1];
    int c0 = 0, c1 = 0, c2 = 0;
    for (int e = e0; e < e1; ++e) {
        int r = edges[e] >> 20;
        c0 += (r == 0); c1 += (r == 1); c2 += (r == 2);
    }
    float inv0 = 1.f / fmaxf((float)c0, 1.f);
    float inv1 = 1.f / fmaxf((float)c1, 1.f);
    float inv2 = 1.f / fmaxf((float)c2, 1.f);

    float acc[24];
    {
        const float4* tr = (const float4*)(Troot + (size_t)key2[i] * 24);
        #pragma unroll
        for (int q = 0; q < 6; ++q) {
            float4 v = tr[q];
            acc[q*4+0]=v.x; acc[q*4+1]=v.y; acc[q*4+2]=v.z; acc[q*4+3]=v.w;
        }
    }
    for (int e = e0; e < e1; ++e) {
        unsigned sl = edges[e];
        int s = sl & 0xFFFFF;
        int r = sl >> 20;
        float w = (r == 0) ? inv0 : ((r == 1) ? inv1 : inv2);
        const float4* trow = (const float4*)(T + ((size_t)r * ntype + key2[s]) * 24);
        #pragma unroll
        for (int q = 0; q < 6; ++q) {
            float4 v = trow[q];
            acc[q*4+0] = fmaf(v.x, w, acc[q*4+0]);
            acc[q*4+1] = fmaf(v.y, w, acc[q*4+1]);
            acc[q*4+2] = fmaf(v.z, w, acc[q*4+2]);
            acc[q*4+3] = fmaf(v.w, w, acc[q*4+3]);
        }
    }
    unsigned ow[12];
    #pragma unroll
    for (int q = 0; q < 12; ++q)
        ow[q] = pack2(fmaxf(acc[2*q], 0.f), fmaxf(acc[2*q+1], 0.f));
    uint4* op = (uint4*)(xout + (size_t)i * 24);
    #pragma unroll
    for (int q = 0; q < 3; ++q) op[q] = ((uint4*)ow)[q];
}

// ===========================================================================
// Layers 1..3, pull: fp16 feature gathers, fp32 accumulate; per-rel VGPR
// accumulators (3-way branch); counts folded in, divide once per node.
// ===========================================================================
template<int DIN, int DOUT, bool FINAL>
__global__ void __launch_bounds__(256) k_layer_pull(
    const __half* __restrict__ xin,
    __half* __restrict__ xout,
    const int* __restrict__ rowptr, const unsigned* __restrict__ edges,
    const float* __restrict__ W,     // [3,DIN,DOUT]
    const float* __restrict__ root,  // [DIN,DOUT]
    const float* __restrict__ bias,  // [DOUT]
    const float* __restrict__ linw,  // [4,2]
    const float* __restrict__ linb,  // [2]
    float* __restrict__ finout, int n)
{
    int j = blockIdx.x * blockDim.x + threadIdx.x;
    if (j >= n) return;

    float a0[DIN], a1[DIN], a2[DIN];
    #pragma unroll
    for (int k = 0; k < DIN; ++k) { a0[k] = 0.f; a1[k] = 0.f; a2[k] = 0.f; }
    int c0 = 0, c1 = 0, c2 = 0;

    int e0 = rowptr[j], e1 = rowptr[j+1];
    for (int e = e0; e < e1; ++e) {
        unsigned sl = edges[e];
        int s = sl & 0xFFFFF;
        int r = sl >> 20;
        const uint4* p = (const uint4*)(xin + (size_t)s * DIN);
        float xs[DIN];
        #pragma unroll
        for (int q = 0; q < DIN/8; ++q) unpack8(p[q], xs + q*8);
        if (r == 0) {
            ++c0;
            #pragma unroll
            for (int k = 0; k < DIN; ++k) a0[k] += xs[k];
        } else if (r == 1) {
            ++c1;
            #pragma unroll
            for (int k = 0; k < DIN; ++k) a1[k] += xs[k];
        } else {
            ++c2;
            #pragma unroll
            for (int k = 0; k < DIN; ++k) a2[k] += xs[k];
        }
    }
    {
        float inv0 = 1.f / fmaxf((float)c0, 1.f);
        float inv1 = 1.f / fmaxf((float)c1, 1.f);
        float inv2 = 1.f / fmaxf((float)c2, 1.f);
        #pragma unroll
        for (int k = 0; k < DIN; ++k) { a0[k] *= inv0; a1[k] *= inv1; a2[k] *= inv2; }
    }

    float o[DOUT];
    #pragma unroll
    for (int d = 0; d < DOUT; ++d) o[d] = bias[d];

    {   // self/root term
        const uint4* p = (const uint4*)(xin + (size_t)j * DIN);
        float xi[DIN];
        #pragma unroll
        for (int q = 0; q < DIN/8; ++q) unpack8(p[q], xi + q*8);
        #pragma unroll
        for (int k = 0; k < DIN; ++k) {
            #pragma unroll
            for (int d = 0; d < DOUT; ++d)
                o[d] = fmaf(xi[k], root[k*DOUT + d], o[d]);
        }
    }
    #pragma unroll
    for (int k = 0; k < DIN; ++k) {
        #pragma unroll
        for (int d = 0; d < DOUT; ++d)
            o[d] = fmaf(a0[k], W[(0*DIN + k)*DOUT + d], o[d]);
    }
    #pragma unroll
    for (int k = 0; k < DIN; ++k) {
        #pragma unroll
        for (int d = 0; d < DOUT; ++d)
            o[d] = fmaf(a1[k], W[(1*DIN + k)*DOUT + d], o[d]);
    }
    #pragma unroll
    for (int k = 0; k < DIN; ++k) {
        #pragma unroll
        for (int d = 0; d < DOUT; ++d)
            o[d] = fmaf(a2[k], W[(2*DIN + k)*DOUT + d], o[d]);
    }
    #pragma unroll
    for (int d = 0; d < DOUT; ++d) o[d] = fmaxf(o[d], 0.f);

    if (FINAL) {                               // DOUT == 4; fp32 output
        float o0 = linb[0], o1 = linb[1];
        #pragma unroll
        for (int k = 0; k < 4; ++k) {
            o0 = fmaf(o[k], linw[k*2+0], o0);
            o1 = fmaf(o[k], linw[k*2+1], o1);
        }
        *(float2*)(finout + (size_t)j * 2) = make_float2(o0, o1);
    } else {
        unsigned ow[DOUT/2];
        #pragma unroll
        for (int q = 0; q < DOUT/2; ++q) ow[q] = pack2(o[2*q], o[2*q+1]);
        uint4* op = (uint4*)(xout + (size_t)j * DOUT);
        #pragma unroll
        for (int q = 0; q < DOUT/8; ++q) op[q] = ((uint4*)ow)[q];
    }
}

// ===========================================================================
extern "C" void kernel_launch(void* const* d_in, const int* in_sizes, int n_in,
                              void* d_out, int out_size, void* d_ws, size_t ws_size,
                              hipStream_t stream)
{
    const int*   x_code    = (const int*)d_in[0];
    const int*   x_size    = (const int*)d_in[1];
    const int*   edge_index= (const int*)d_in[2];
    const int*   edge_type = (const int*)d_in[3];
    const float* size_emb  = (const float*)d_in[4];
    const float* code_emb  = (const float*)d_in[5];
    const float* w0 = (const float*)d_in[6];  const float* root0 = (const float*)d_in[7];  const float* b0 = (const float*)d_in[8];
    const float* w1 = (const float*)d_in[9];  const float* root1 = (const float*)d_in[10]; const float* b1 = (const float*)d_in[11];
    const float* w2 = (const float*)d_in[12]; const float* root2 = (const float*)d_in[13]; const float* b2 = (const float*)d_in[14];
    const float* w3 = (const float*)d_in[15]; const float* root3 = (const float*)d_in[16]; const float* b3 = (const float*)d_in[17];
    const float* lin_w = (const float*)d_in[18];
    const float* lin_b = (const float*)d_in[19];

    int n  = in_sizes[0];
    int E  = in_sizes[3];
    int ns = in_sizes[4] / 4;    // 15
    int nc = in_sizes[5] / 32;   // 202
    int ntype = ns * nc;         // 3030
    const int* esrc = edge_index;
    const int* edst = edge_index + E;

    int NB  = (n + BKT_MASK) >> BKT_SHIFT;     // buckets (977)
    int NBK = (E + EPB - 1) / EPB;             // partition blocks (977)
    int m   = NB * NBK;                        // histT elements (~955K)

    // workspace carve-up (~115 MB)
    char* ws = (char*)d_ws;
    size_t off = 0;
    auto alloc = [&](size_t bytes) -> void* {
        void* p = ws + off;
        off = (off + bytes + 255) & ~(size_t)255;
        return p;
    };
    __half*   bufA     = (__half*)  alloc((size_t)n * 24 * 2);   // x1, later x3
    __half*   bufB     = (__half*)  alloc((size_t)n * 16 * 2);   // x2
    int*      rowptr   = (int*)     alloc(((size_t)n + 1) * 4);
    unsigned* edges    = (unsigned*)alloc((size_t)E * 4);        // final CSR slots
    unsigned* tmp      = (unsigned*)alloc((size_t)E * 4);        // partitioned
    int*      histT    = (int*)     alloc((size_t)m * 4);        // [bucket][block]
    int*      key2     = (int*)     alloc((size_t)n * 4);
    int*      partials = (int*)     alloc(4096 * 4);
    float*    T        = (float*)   alloc((size_t)NREL * ntype * 24 * 4);
    float*    Troot    = (float*)   alloc((size_t)ntype * 24 * 4);

    const int tb = 256;
    int tableThreads = NREL*ntype*24 + ntype*24;
    k_tables2<<<(tableThreads + tb - 1)/tb, tb, 0, stream>>>(
        size_emb, code_emb, w0, root0, b0, T, Troot, ns, nc);
    k_key<<<(n + tb - 1)/tb, tb, 0, stream>>>(x_size, x_code, key2, n, nc);

    // ---- atomic-free CSR build ----
    k_hist<<<NBK, tb, 0, stream>>>(edst, histT, E, NB, NBK);
    int nblk = (m + 1023) / 1024;              // ~933 (<=1024)
    kscan1<<<nblk, tb, 0, stream>>>(histT, partials, m);
    kscan2<<<1, 1024, 0, stream>>>(partials, nblk);
    kscan3<<<nblk, tb, 0, stream>>>(histT, partials, m);
    k_scatter<<<NBK, tb, 0, stream>>>(esrc, edst, edge_type, histT, tmp, E, NB, NBK);
    k_csr<<<NB, tb, 0, stream>>>(tmp, histT, rowptr, edges, n, E, NB, NBK);

    // ---- layers ----
    int g256 = (n + 255) / 256;
    k_layer0_pull<<<g256, tb, 0, stream>>>(key2, rowptr, edges, T, Troot, bufA, n, ntype);
    k_layer_pull<24,16,false><<<g256, tb, 0, stream>>>(bufA, bufB, rowptr, edges,
                                                 w1, root1, b1, nullptr, nullptr, nullptr, n);
    k_layer_pull<16, 8,false><<<g256, tb, 0, stream>>>(bufB, bufA, rowptr, edges,
                                                 w2, root2, b2, nullptr, nullptr, nullptr, n);
    k_layer_pull< 8, 4,true ><<<g256, tb, 0, stream>>>(bufA, nullptr, rowptr, edges,
                                                 w3, root3, b3, lin_w, lin_b, (float*)d_out, n);
}